// Round 13
// baseline (85.230 us; speedup 1.0000x reference)
//
#include <hip/hip_runtime.h>
#include <hip/hip_bf16.h>
#include <math.h>

#define NHEADS 12

typedef __attribute__((ext_vector_type(4))) float f32x4;
typedef __attribute__((ext_vector_type(16))) float f32x16;
typedef __attribute__((ext_vector_type(8))) short bf16x8;

__device__ __forceinline__ unsigned short f2bf(float x) {
  __hip_bfloat16 h = __float2bfloat16(x);
  return *reinterpret_cast<unsigned short*>(&h);
}
__device__ __forceinline__ float bf2f(unsigned short u) {
  union { unsigned int i; float f; } c; c.i = ((unsigned int)u) << 16; return c.f;
}

// Bijective XCD-chunk remap (m204): contiguous wgid chunk per XCD.
__device__ __forceinline__ int xcd_swz(int orig, int nwg) {
  int q = nwg >> 3, r = nwg & 7;
  int xcd = orig & 7, idx = orig >> 3;
  return (xcd < r ? xcd * (q + 1) : r * (q + 1) + (xcd - r) * q) + idx;
}

// ---------------------------------------------------------------------------
// Kernel 1 "prep": weight transpose+convert (bx < nw); nonzero-compaction
// scan + bkv concat (bx == nw).
// ---------------------------------------------------------------------------
__global__ __launch_bounds__(256) void prep(const float* __restrict__ mask, int total,
                                            int* __restrict__ pos2l, int* __restrict__ lidx,
                                            const float* __restrict__ bk, const float* __restrict__ bv,
                                            float* __restrict__ bkv,
                                            const float* __restrict__ W0, const float* __restrict__ W1,
                                            const float* __restrict__ W2, const float* __restrict__ W3,
                                            unsigned short* __restrict__ T0, unsigned short* __restrict__ T1,
                                            unsigned short* __restrict__ T2, unsigned short* __restrict__ T3,
                                            int H) {
  int nt32 = H / 32;
  int nw = nt32 * nt32 * 4;
  int bx = blockIdx.x;
  int t = threadIdx.x;
  if (bx < nw) {
    __shared__ float tile[32][33];
    int z = bx / (nt32 * nt32);
    int rem = bx - z * nt32 * nt32;
    int byy = rem / nt32;
    int bxx = rem - byy * nt32;
    const float* W = (z == 0) ? W0 : (z == 1) ? W1 : (z == 2) ? W2 : W3;
    unsigned short* T = (z == 0) ? T0 : (z == 1) ? T1 : (z == 2) ? T2 : T3;
    int k0 = byy * 32, n0 = bxx * 32;
    int kk = t >> 3, n4 = (t & 7) * 4;
    float4 v = *reinterpret_cast<const float4*>(W + (size_t)(k0 + kk) * H + n0 + n4);
    tile[n4 + 0][kk] = v.x; tile[n4 + 1][kk] = v.y; tile[n4 + 2][kk] = v.z; tile[n4 + 3][kk] = v.w;
    __syncthreads();
    int nn2 = t >> 3, k4 = (t & 7) * 4;
#pragma unroll
    for (int e = 0; e < 4; ++e)
      T[(size_t)(n0 + nn2) * H + k0 + k4 + e] = f2bf(tile[nn2][k4 + e]);
  } else {
    __shared__ int cnt[256];
    for (int i = t; i < H; i += 256) { bkv[i] = bk[i]; bkv[H + i] = bv[i]; }
    int per = (total + 255) >> 8;
    int begin = t * per;
    int end = begin + per; if (end > total) end = total;
    if (begin > total) begin = total;
    int c = 0;
    for (int i = begin; i < end; ++i) c += (mask[i] > 0.f) ? 1 : 0;
    cnt[t] = c;
    __syncthreads();
    for (int off = 1; off < 256; off <<= 1) {
      int vv = (t >= off) ? cnt[t - off] : 0;
      __syncthreads();
      cnt[t] += vv;
      __syncthreads();
    }
    int excl = cnt[t] - c;
    for (int i = begin; i < end; ++i) {
      if (mask[i] > 0.f) { pos2l[i] = excl; lidx[excl] = i; ++excl; }
      else pos2l[i] = -1;
    }
  }
}

// ---------------------------------------------------------------------------
// 128x128 MFMA GEMM core, DOUBLE-BUFFERED with ONE barrier per K-step +
// T14 issue-early/write-late A-path. 64 KB LDS (free: occupancy is
// grid-limited at 1.76 blocks/CU). 4 waves 2x2, 2x2 frags of 32x32x16.
// fp32 A gather (loads for t+1 issued BEFORE compute(t), cvt+ds_write
// AFTER — compiler places the dependent waitcnt post-MFMA); B via
// global_load_lds (drained by the next iteration's barrier, a full
// compute-phase after issue).
// ---------------------------------------------------------------------------
#define QBM 128
#define QBN 128
#define QBK 64

__device__ __forceinline__ void gemm128_f32a_core(const float* __restrict__ A,
                                                  const int* __restrict__ lidx,
                                                  const unsigned short* __restrict__ Bt,
                                                  const float* __restrict__ bias,
                                                  unsigned short* __restrict__ C,
                                                  int M, int N, int K, int m0, int n0,
                                                  unsigned short* sA, unsigned short* sB) {
  int tid = threadIdx.x;
  int wid = tid >> 6, lane = tid & 63;
  int wm = wid >> 1, wn = wid & 1;
  int lane31 = lane & 31, laneh = lane >> 5;
  f32x16 acc[2][2] = {};

  const float* aptr[4];
  const unsigned short* bptr[4];
  int ldsoff[4];
#pragma unroll
  for (int r = 0; r < 4; ++r) {
    int c = (r * 4 + wid) * 64 + lane;
    int row = c >> 3, sl = c & 7;
    int sg = sl ^ (row & 7);
    int gm = m0 + row; if (gm >= M) gm = M - 1;
    aptr[r] = A + (size_t)lidx[gm] * K + sg * 8;
    bptr[r] = Bt + (size_t)(n0 + row) * K + sg * 8;
    ldsoff[r] = c * 8;
  }

  const int nt = K / QBK;
  // prologue: tile 0 -> buf 0
#pragma unroll
  for (int r = 0; r < 4; ++r)
    __builtin_amdgcn_global_load_lds((const __attribute__((address_space(1))) unsigned int*)bptr[r],
                                     (__attribute__((address_space(3))) unsigned int*)(sB + (r * 4 + wid) * 512),
                                     16, 0, 0);
  {
    bf16x8 st[4];
#pragma unroll
    for (int r = 0; r < 4; ++r) {
      f32x4 a = *reinterpret_cast<const f32x4*>(aptr[r]);
      f32x4 b = *reinterpret_cast<const f32x4*>(aptr[r] + 4);
#pragma unroll
      for (int e = 0; e < 4; ++e) { st[r][e] = f2bf(a[e]); st[r][4 + e] = f2bf(b[e]); }
    }
#pragma unroll
    for (int r = 0; r < 4; ++r)
      *reinterpret_cast<bf16x8*>(sA + ldsoff[r]) = st[r];
  }

  int cur = 0;
  for (int t = 0; t < nt; ++t) {
    __syncthreads();                       // buf[cur] ready; drains B(t) (+B(t-1..)) a full phase after issue
    int k1 = (t + 1) * QBK;
    bool more = (t + 1 < nt);
    f32x4 an[4], bn[4];
    if (more) {
      // issue next A-tile loads early (consumed only after compute)
#pragma unroll
      for (int r = 0; r < 4; ++r) {
        an[r] = *reinterpret_cast<const f32x4*>(aptr[r] + k1);
        bn[r] = *reinterpret_cast<const f32x4*>(aptr[r] + k1 + 4);
      }
      // issue next B-tile direct-to-LDS (lands before next barrier)
#pragma unroll
      for (int r = 0; r < 4; ++r)
        __builtin_amdgcn_global_load_lds((const __attribute__((address_space(1))) unsigned int*)(bptr[r] + k1),
                                         (__attribute__((address_space(3))) unsigned int*)(sB + (cur ^ 1) * (QBN * QBK) + (r * 4 + wid) * 512),
                                         16, 0, 0);
    }
    const unsigned short* pA = sA + cur * (QBM * QBK);
    const unsigned short* pB = sB + cur * (QBN * QBK);
#pragma unroll
    for (int ks = 0; ks < 4; ++ks) {
      bf16x8 af[2], bfr[2];
#pragma unroll
      for (int i = 0; i < 2; ++i) {
        int row = wm * 64 + i * 32 + lane31;
        int slot = (ks * 2 + laneh) ^ (row & 7);
        af[i] = *reinterpret_cast<const bf16x8*>(pA + row * 64 + slot * 8);
      }
#pragma unroll
      for (int j = 0; j < 2; ++j) {
        int rn = wn * 64 + j * 32 + lane31;
        int slot = (ks * 2 + laneh) ^ (rn & 7);
        bfr[j] = *reinterpret_cast<const bf16x8*>(pB + rn * 64 + slot * 8);
      }
#pragma unroll
      for (int i = 0; i < 2; ++i)
#pragma unroll
        for (int j = 0; j < 2; ++j)
          acc[i][j] = __builtin_amdgcn_mfma_f32_32x32x16_bf16(af[i], bfr[j], acc[i][j], 0, 0, 0);
    }
    if (more) {
      // write-late: cvt + ds_write into buf[cur^1] (after MFMA, before barrier)
      bf16x8 st[4];
#pragma unroll
      for (int r = 0; r < 4; ++r) {
#pragma unroll
        for (int e = 0; e < 4; ++e) { st[r][e] = f2bf(an[r][e]); st[r][4 + e] = f2bf(bn[r][e]); }
      }
#pragma unroll
      for (int r = 0; r < 4; ++r)
        *reinterpret_cast<bf16x8*>(sA + (cur ^ 1) * (QBM * QBK) + ldsoff[r]) = st[r];
    }
    cur ^= 1;
  }

#pragma unroll
  for (int i = 0; i < 2; ++i) {
#pragma unroll
    for (int j = 0; j < 2; ++j) {
      int gcol = n0 + wn * 64 + j * 32 + lane31;
      float bv = bias[gcol];
#pragma unroll
      for (int r = 0; r < 16; ++r) {
        int gm = m0 + wm * 64 + i * 32 + (r & 3) + ((r >> 2) << 3) + (laneh << 2);
        if (gm >= M) continue;
        C[(size_t)gm * N + gcol] = f2bf(acc[i][j][r] + bv);
      }
    }
  }
}

__global__ __launch_bounds__(256) void gemm_qkv(const float* __restrict__ hidden,
                                                const float* __restrict__ input,
                                                const unsigned short* __restrict__ Wqt,
                                                const unsigned short* __restrict__ Wkvt,
                                                const float* __restrict__ bq,
                                                const float* __restrict__ bkv,
                                                const int* __restrict__ lidx,
                                                unsigned short* __restrict__ Cq,
                                                unsigned short* __restrict__ Ckv,
                                                int M, int K, int H, int NX) {
  __shared__ unsigned short sA[2 * QBM * QBK];
  __shared__ unsigned short sB[2 * QBN * QBK];
  int wgid = xcd_swz(blockIdx.x, gridDim.x);
  int y = wgid / NX, x = wgid - y * NX;
  int m0 = y * QBM;
  int nq = H / QBN;
  if (x < nq)
    gemm128_f32a_core(hidden, lidx, Wqt, bq, Cq, M, H, K, m0, x * QBN, sA, sB);
  else
    gemm128_f32a_core(input, lidx, Wkvt, bkv, Ckv, M, 2 * H, K, m0, (x - nq) * QBN, sA, sB);
}

// ---------------------------------------------------------------------------
// 128x64 MFMA GEMM for the output projection, double-buffered one-barrier
// (48 KB LDS, grid-limited occupancy unaffected). bf16 A via
// global_load_lds, fp32 output.
// ---------------------------------------------------------------------------
#define GBM 128
#define GBN 64
#define GBK 64

__global__ __launch_bounds__(256) void gemm_out(const unsigned short* __restrict__ A,
                                                const unsigned short* __restrict__ Bt,
                                                const float* __restrict__ bias,
                                                float* __restrict__ C,
                                                int M, int N, int K) {
  __shared__ unsigned short sA[2 * GBM * GBK];
  __shared__ unsigned short sB[2 * GBN * GBK];
  int NX = N / GBN;
  int wgid = xcd_swz(blockIdx.x, gridDim.x);
  int y = wgid / NX, x = wgid - y * NX;
  int m0 = y * GBM, n0 = x * GBN;
  int tid = threadIdx.x;
  int wid = tid >> 6, lane = tid & 63;
  int wm = wid >> 1, wn = wid & 1;
  int lane31 = lane & 31, laneh = lane >> 5;
  f32x16 acc[2] = {};

  const unsigned short* aptr[4];
  const unsigned short* bptr[2];
#pragma unroll
  for (int r = 0; r < 4; ++r) {
    int c = (r * 4 + wid) * 64 + lane;
    int row = c >> 3, sl = c & 7;
    int sg = sl ^ (row & 7);
    aptr[r] = A + (size_t)(m0 + row) * K + sg * 8;
    if (r < 2) bptr[r] = Bt + (size_t)(n0 + row) * K + sg * 8;
  }

  auto STAGE = [&](int buf, int k0) {
#pragma unroll
    for (int r = 0; r < 4; ++r)
      __builtin_amdgcn_global_load_lds((const __attribute__((address_space(1))) unsigned int*)(aptr[r] + k0),
                                       (__attribute__((address_space(3))) unsigned int*)(sA + buf * (GBM * GBK) + (r * 4 + wid) * 512),
                                       16, 0, 0);
#pragma unroll
    for (int r = 0; r < 2; ++r)
      __builtin_amdgcn_global_load_lds((const __attribute__((address_space(1))) unsigned int*)(bptr[r] + k0),
                                       (__attribute__((address_space(3))) unsigned int*)(sB + buf * (GBN * GBK) + (r * 4 + wid) * 512),
                                       16, 0, 0);
  };

  const int nt = K / GBK;
  STAGE(0, 0);
  int cur = 0;
  for (int t = 0; t < nt; ++t) {
    __syncthreads();                      // buf[cur] landed (issued one phase ago)
    if (t + 1 < nt) STAGE(cur ^ 1, (t + 1) * GBK);
    const unsigned short* pA = sA + cur * (GBM * GBK);
    const unsigned short* pB = sB + cur * (GBN * GBK);
#pragma unroll
    for (int ks = 0; ks < 4; ++ks) {
      bf16x8 af[2], bfr;
#pragma unroll
      for (int i = 0; i < 2; ++i) {
        int row = wm * 64 + i * 32 + lane31;
        int slot = (ks * 2 + laneh) ^ (row & 7);
        af[i] = *reinterpret_cast<const bf16x8*>(pA + row * 64 + slot * 8);
      }
      {
        int rn = wn * 32 + lane31;
        int slot = (ks * 2 + laneh) ^ (rn & 7);
        bfr = *reinterpret_cast<const bf16x8*>(pB + rn * 64 + slot * 8);
      }
#pragma unroll
      for (int i = 0; i < 2; ++i)
        acc[i] = __builtin_amdgcn_mfma_f32_32x32x16_bf16(af[i], bfr, acc[i], 0, 0, 0);
    }
    cur ^= 1;
  }

#pragma unroll
  for (int i = 0; i < 2; ++i) {
    int gcol = n0 + wn * 32 + lane31;
    float bv = bias[gcol];
#pragma unroll
    for (int r = 0; r < 16; ++r) {
      int gm = m0 + wm * 64 + i * 32 + (r & 3) + ((r >> 2) << 3) + (laneh << 2);
      if (gm >= M) continue;
      C[(size_t)gm * N + gcol] = acc[i][r] + bv;
    }
  }
}

// ---------------------------------------------------------------------------
// Kernel 5: criss-cross attention (round-12 lane-utilization version).
// ---------------------------------------------------------------------------
__global__ __launch_bounds__(128) void attn3(const unsigned short* __restrict__ qb,
                                             const unsigned short* __restrict__ KVb,
                                             const float* __restrict__ mask,
                                             const int* __restrict__ pos2l,
                                             unsigned short* __restrict__ ctx,
                                             int n, int H) {
  __shared__ unsigned short Ks[40 * 72];
  __shared__ unsigned short Vs[40 * 72];
  __shared__ float S[40][44];
  __shared__ float Sinv[40];
  __shared__ float mrow[40];
  __shared__ int qlist[40];

  int bx = blockIdx.x;
  int r0 = bx % n;
  int h3 = (bx / n) % 3;
  int p = (bx / (3 * n)) % 4;
  int bi = bx / (12 * n);
  int h = p + 4 * h3;
  int nn = n * n;
  bool rowkeys = (p == 0 || p == 3);
  bool rowq = (p == 0 || p == 2);
  bool excl = (p < 2);
  int t = threadIdx.x;
  int H2 = 2 * H;

#pragma unroll
  for (int i = 0; i < 5; ++i) {
    int c2 = t + 128 * i;
    int jr = c2 >> 3, e8 = c2 & 7;
    int half = jr >= 40 ? 1 : 0;
    int j = jr - half * 40;
    int keypos = rowkeys ? (r0 * n + j) : (j * n + r0);
    int l2 = pos2l[bi * nn + keypos];
    bf16x8 v = {};
    if (l2 >= 0)
      v = *reinterpret_cast<const bf16x8*>(KVb + (size_t)l2 * H2 + half * H + h * 64 + e8 * 8);
    *reinterpret_cast<bf16x8*>((half ? Vs : Ks) + j * 72 + e8 * 8) = v;
  }
  if (t < 40) {
    mrow[t] = rowkeys ? mask[bi * nn + r0 * n + t] : mask[bi * nn + t * n + r0];
    int qpos = rowq ? (r0 * n + t) : (t * n + r0);
    qlist[t] = pos2l[bi * nn + qpos];
  }
  __syncthreads();

  int c = t % 40;
  int role = t / 40;
  int lq = (t < 120) ? qlist[c] : -1;

  if (lq >= 0) {
    float qf[64];
    const unsigned short* qp = qb + (size_t)lq * H + h * 64;
#pragma unroll
    for (int e8 = 0; e8 < 8; ++e8) {
      bf16x8 t8 = *reinterpret_cast<const bf16x8*>(qp + e8 * 8);
#pragma unroll
      for (int e = 0; e < 8; ++e) qf[e8 * 8 + e] = bf2f((unsigned short)t8[e]);
    }
    int j0 = role * 14;
    int j1 = j0 + 14; if (j1 > 40) j1 = 40;
    for (int j = j0; j < j1; ++j) {
      float acc = 0.f;
#pragma unroll
      for (int e8 = 0; e8 < 8; ++e8) {
        bf16x8 kv = *reinterpret_cast<const bf16x8*>(Ks + j * 72 + e8 * 8);
#pragma unroll
        for (int e = 0; e < 8; ++e) acc = fmaf(qf[e8 * 8 + e], bf2f((unsigned short)kv[e]), acc);
      }
      float mval = mrow[j] * ((excl && j == c) ? 0.f : 1.f);
      S[c][j] = acc * 0.125f + (1.f - mval) * -10000.f;
    }
    if (role == 2) {
      const unsigned short* kp = KVb + (size_t)lq * H2 + h * 64;
      float acc = 0.f;
#pragma unroll
      for (int e8 = 0; e8 < 8; ++e8) {
        bf16x8 kv = *reinterpret_cast<const bf16x8*>(kp + e8 * 8);
#pragma unroll
        for (int e = 0; e < 8; ++e) acc = fmaf(qf[e8 * 8 + e], bf2f((unsigned short)kv[e]), acc);
      }
      S[c][40] = acc * 0.125f + 1.0f;
    }
  }
  __syncthreads();

  if (t < 40 && qlist[t] >= 0) {
    float mx = S[t][0];
    for (int j = 1; j <= 40; ++j) mx = fmaxf(mx, S[t][j]);
    float sum = 0.f;
    for (int j = 0; j <= 40; ++j) { float e = __expf(S[t][j] - mx); S[t][j] = e; sum += e; }
    Sinv[t] = 1.f / sum;
  }
  __syncthreads();

  if (t < 80 && lq >= 0) {
    int d0 = role * 32;
    const unsigned short* vsp = KVb + (size_t)lq * H2 + H + h * 64 + d0;
    float pself = S[c][40];
    float inv = Sinv[c];
#pragma unroll
    for (int ch = 0; ch < 4; ++ch) {
      int dd = d0 + ch * 8;
      float facc[8];
      bf16x8 vself = *reinterpret_cast<const bf16x8*>(vsp + ch * 8);
#pragma unroll
      for (int e = 0; e < 8; ++e) facc[e] = pself * bf2f((unsigned short)vself[e]);
      for (int j = 0; j < 40; ++j) {
        float pj = S[c][j];
        bf16x8 vv = *reinterpret_cast<const bf16x8*>(Vs + j * 72 + dd);
#pragma unroll
        for (int e = 0; e < 8; ++e) facc[e] = fmaf(pj, bf2f((unsigned short)vv[e]), facc[e]);
      }
      bf16x8 st;
#pragma unroll
      for (int e = 0; e < 8; ++e) st[e] = f2bf(facc[e] * inv);
      *reinterpret_cast<bf16x8*>(ctx + (size_t)lq * H + h * 64 + dd) = st;
    }
  }
}

// ---------------------------------------------------------------------------
extern "C" void kernel_launch(void* const* d_in, const int* in_sizes, int n_in,
                              void* d_out, int out_size, void* d_ws, size_t ws_size,
                              hipStream_t stream) {
  const float* Input  = (const float*)d_in[0];
  const float* hidden = (const float*)d_in[1];
  const float* mask   = (const float*)d_in[2];
  const float* Wq = (const float*)d_in[3];
  const float* bq = (const float*)d_in[4];
  const float* Wk = (const float*)d_in[5];
  const float* bk = (const float*)d_in[6];
  const float* Wv = (const float*)d_in[7];
  const float* bv = (const float*)d_in[8];
  const float* Wo = (const float*)d_in[9];
  const float* bo = (const float*)d_in[10];

  int H = (int)llround(sqrt((double)in_sizes[3]));   // 768
  int total = in_sizes[2];                           // b*n*n = 3200
  int L = out_size / H;                              // 3120
  int bn = total - L;                                // b*n = 80
  int n = total / bn;                                // 40
  int b = bn / n;                                    // 2
  int mtiles = (L + QBM - 1) / QBM;                  // 25
  int Mpad = mtiles * QBM;                           // 3200
  size_t aElems = (size_t)Mpad * H;

  char* p = (char*)d_ws;
  auto take = [&](size_t bytes) { char* r = p; p += (bytes + 255) & ~(size_t)255; return r; };
  int* lidx  = (int*)take((size_t)L * 4);
  int* pos2l = (int*)take((size_t)total * 4);
  float* bkv = (float*)take((size_t)2 * H * 4);
  unsigned short* Wqt  = (unsigned short*)take((size_t)H * H * 2);
  unsigned short* Wot  = (unsigned short*)take((size_t)H * H * 2);
  unsigned short* Wkvt = (unsigned short*)take((size_t)2 * H * H * 2);
  unsigned short* qb2  = (unsigned short*)take(aElems * 2);
  unsigned short* KVb  = (unsigned short*)take(aElems * 2 * 2);
  unsigned short* ctxb = (unsigned short*)take(aElems * 2);

  int nt32 = H / 32;
  int nwconv = nt32 * nt32 * 4;                      // 2304
  prep<<<nwconv + 1, 256, 0, stream>>>(mask, total, pos2l, lidx, bk, bv, bkv,
                                       Wq, Wk, Wv, Wo,
                                       Wqt, Wkvt, Wkvt + (size_t)H * H, Wot, H);
  {
    int NX = 3 * H / QBN;                            // 18
    gemm_qkv<<<NX * mtiles, 256, 0, stream>>>(hidden, Input, Wqt, Wkvt, bq, bkv, lidx,
                                              qb2, KVb, L, H, H, NX);
  }
  attn3<<<b * 4 * 3 * n, 128, 0, stream>>>(qb2, KVb, mask, pos2l, ctxb, n, H);
  gemm_out<<<(H / GBN) * mtiles, 256, 0, stream>>>(ctxb, Wot, bo, (float*)d_out, L, H, H);
}

// Round 14
// 84.111 us; speedup vs baseline: 1.0133x; 1.0133x over previous
//
#include <hip/hip_runtime.h>
#include <hip/hip_bf16.h>
#include <math.h>

#define NHEADS 12

typedef __attribute__((ext_vector_type(4))) float f32x4;
typedef __attribute__((ext_vector_type(16))) float f32x16;
typedef __attribute__((ext_vector_type(8))) short bf16x8;

__device__ __forceinline__ unsigned short f2bf(float x) {
  __hip_bfloat16 h = __float2bfloat16(x);
  return *reinterpret_cast<unsigned short*>(&h);
}
__device__ __forceinline__ float bf2f(unsigned short u) {
  union { unsigned int i; float f; } c; c.i = ((unsigned int)u) << 16; return c.f;
}

// Bijective XCD-chunk remap (m204): contiguous wgid chunk per XCD.
__device__ __forceinline__ int xcd_swz(int orig, int nwg) {
  int q = nwg >> 3, r = nwg & 7;
  int xcd = orig & 7, idx = orig >> 3;
  return (xcd < r ? xcd * (q + 1) : r * (q + 1) + (xcd - r) * q) + idx;
}

// ---------------------------------------------------------------------------
// Kernel 1 "prep": weight transpose+convert (bx < nw); nonzero-compaction
// scan + bkv concat (bx == nw).
// ---------------------------------------------------------------------------
__global__ __launch_bounds__(256) void prep(const float* __restrict__ mask, int total,
                                            int* __restrict__ pos2l, int* __restrict__ lidx,
                                            const float* __restrict__ bk, const float* __restrict__ bv,
                                            float* __restrict__ bkv,
                                            const float* __restrict__ W0, const float* __restrict__ W1,
                                            const float* __restrict__ W2, const float* __restrict__ W3,
                                            unsigned short* __restrict__ T0, unsigned short* __restrict__ T1,
                                            unsigned short* __restrict__ T2, unsigned short* __restrict__ T3,
                                            int H) {
  int nt32 = H / 32;
  int nw = nt32 * nt32 * 4;
  int bx = blockIdx.x;
  int t = threadIdx.x;
  if (bx < nw) {
    __shared__ float tile[32][33];
    int z = bx / (nt32 * nt32);
    int rem = bx - z * nt32 * nt32;
    int byy = rem / nt32;
    int bxx = rem - byy * nt32;
    const float* W = (z == 0) ? W0 : (z == 1) ? W1 : (z == 2) ? W2 : W3;
    unsigned short* T = (z == 0) ? T0 : (z == 1) ? T1 : (z == 2) ? T2 : T3;
    int k0 = byy * 32, n0 = bxx * 32;
    int kk = t >> 3, n4 = (t & 7) * 4;
    float4 v = *reinterpret_cast<const float4*>(W + (size_t)(k0 + kk) * H + n0 + n4);
    tile[n4 + 0][kk] = v.x; tile[n4 + 1][kk] = v.y; tile[n4 + 2][kk] = v.z; tile[n4 + 3][kk] = v.w;
    __syncthreads();
    int nn2 = t >> 3, k4 = (t & 7) * 4;
#pragma unroll
    for (int e = 0; e < 4; ++e)
      T[(size_t)(n0 + nn2) * H + k0 + k4 + e] = f2bf(tile[nn2][k4 + e]);
  } else {
    __shared__ int cnt[256];
    for (int i = t; i < H; i += 256) { bkv[i] = bk[i]; bkv[H + i] = bv[i]; }
    int per = (total + 255) >> 8;
    int begin = t * per;
    int end = begin + per; if (end > total) end = total;
    if (begin > total) begin = total;
    int c = 0;
    for (int i = begin; i < end; ++i) c += (mask[i] > 0.f) ? 1 : 0;
    cnt[t] = c;
    __syncthreads();
    for (int off = 1; off < 256; off <<= 1) {
      int vv = (t >= off) ? cnt[t - off] : 0;
      __syncthreads();
      cnt[t] += vv;
      __syncthreads();
    }
    int excl = cnt[t] - c;
    for (int i = begin; i < end; ++i) {
      if (mask[i] > 0.f) { pos2l[i] = excl; lidx[excl] = i; ++excl; }
      else pos2l[i] = -1;
    }
  }
}

// ---------------------------------------------------------------------------
// 128x128 MFMA GEMM core (best config, round 10/12): 256 thr, 4 waves 2x2,
// each wave 64x64 = 2x2 frags of 32x32x16, BK=64, single-buffered 32 KB LDS,
// XOR-swizzled. fp32 A gather+convert (reg-staged ds_write); B via
// global_load_lds.
// ---------------------------------------------------------------------------
#define QBM 128
#define QBN 128
#define QBK 64

__device__ __forceinline__ void gemm128_f32a_core(const float* __restrict__ A,
                                                  const int* __restrict__ lidx,
                                                  const unsigned short* __restrict__ Bt,
                                                  const float* __restrict__ bias,
                                                  unsigned short* __restrict__ C,
                                                  int M, int N, int K, int m0, int n0,
                                                  unsigned short* sA, unsigned short* sB) {
  int tid = threadIdx.x;
  int wid = tid >> 6, lane = tid & 63;
  int wm = wid >> 1, wn = wid & 1;
  int lane31 = lane & 31, laneh = lane >> 5;
  f32x16 acc[2][2] = {};

  const float* aptr[4];
  const unsigned short* bptr[4];
  int ldsoff[4];
#pragma unroll
  for (int r = 0; r < 4; ++r) {
    int c = (r * 4 + wid) * 64 + lane;
    int row = c >> 3, sl = c & 7;
    int sg = sl ^ (row & 7);
    int gm = m0 + row; if (gm >= M) gm = M - 1;
    aptr[r] = A + (size_t)lidx[gm] * K + sg * 8;
    bptr[r] = Bt + (size_t)(n0 + row) * K + sg * 8;
    ldsoff[r] = c * 8;
  }

  for (int k0 = 0; k0 < K; k0 += QBK) {
#pragma unroll
    for (int r = 0; r < 4; ++r)
      __builtin_amdgcn_global_load_lds((const __attribute__((address_space(1))) unsigned int*)(bptr[r] + k0),
                                       (__attribute__((address_space(3))) unsigned int*)(sB + (r * 4 + wid) * 512),
                                       16, 0, 0);
    bf16x8 st[4];
#pragma unroll
    for (int r = 0; r < 4; ++r) {
      f32x4 a = *reinterpret_cast<const f32x4*>(aptr[r] + k0);
      f32x4 b = *reinterpret_cast<const f32x4*>(aptr[r] + k0 + 4);
#pragma unroll
      for (int e = 0; e < 4; ++e) { st[r][e] = f2bf(a[e]); st[r][4 + e] = f2bf(b[e]); }
    }
#pragma unroll
    for (int r = 0; r < 4; ++r)
      *reinterpret_cast<bf16x8*>(sA + ldsoff[r]) = st[r];
    __syncthreads();
#pragma unroll
    for (int ks = 0; ks < 4; ++ks) {
      bf16x8 af[2], bfr[2];
#pragma unroll
      for (int i = 0; i < 2; ++i) {
        int row = wm * 64 + i * 32 + lane31;
        int slot = (ks * 2 + laneh) ^ (row & 7);
        af[i] = *reinterpret_cast<const bf16x8*>(sA + row * 64 + slot * 8);
      }
#pragma unroll
      for (int j = 0; j < 2; ++j) {
        int rn = wn * 64 + j * 32 + lane31;
        int slot = (ks * 2 + laneh) ^ (rn & 7);
        bfr[j] = *reinterpret_cast<const bf16x8*>(sB + rn * 64 + slot * 8);
      }
#pragma unroll
      for (int i = 0; i < 2; ++i)
#pragma unroll
        for (int j = 0; j < 2; ++j)
          acc[i][j] = __builtin_amdgcn_mfma_f32_32x32x16_bf16(af[i], bfr[j], acc[i][j], 0, 0, 0);
    }
    __syncthreads();
  }

#pragma unroll
  for (int i = 0; i < 2; ++i) {
#pragma unroll
    for (int j = 0; j < 2; ++j) {
      int gcol = n0 + wn * 64 + j * 32 + lane31;
      float bv = bias[gcol];
#pragma unroll
      for (int r = 0; r < 16; ++r) {
        int gm = m0 + wm * 64 + i * 32 + (r & 3) + ((r >> 2) << 3) + (laneh << 2);
        if (gm >= M) continue;
        C[(size_t)gm * N + gcol] = f2bf(acc[i][j][r] + bv);
      }
    }
  }
}

__global__ __launch_bounds__(256) void gemm_qkv(const float* __restrict__ hidden,
                                                const float* __restrict__ input,
                                                const unsigned short* __restrict__ Wqt,
                                                const unsigned short* __restrict__ Wkvt,
                                                const float* __restrict__ bq,
                                                const float* __restrict__ bkv,
                                                const int* __restrict__ lidx,
                                                unsigned short* __restrict__ Cq,
                                                unsigned short* __restrict__ Ckv,
                                                int M, int K, int H, int NX) {
  __shared__ unsigned short sA[QBM * QBK];
  __shared__ unsigned short sB[QBN * QBK];
  int wgid = xcd_swz(blockIdx.x, gridDim.x);
  int y = wgid / NX, x = wgid - y * NX;
  int m0 = y * QBM;
  int nq = H / QBN;
  if (x < nq)
    gemm128_f32a_core(hidden, lidx, Wqt, bq, Cq, M, H, K, m0, x * QBN, sA, sB);
  else
    gemm128_f32a_core(input, lidx, Wkvt, bkv, Ckv, M, 2 * H, K, m0, (x - nq) * QBN, sA, sB);
}

// ---------------------------------------------------------------------------
// 128x64 MFMA GEMM (32x32x16) for the output projection: 300 blocks,
// bf16 A via global_load_lds, fp32 output.
// ---------------------------------------------------------------------------
#define GBM 128
#define GBN 64
#define GBK 64

__global__ __launch_bounds__(256) void gemm_out(const unsigned short* __restrict__ A,
                                                const unsigned short* __restrict__ Bt,
                                                const float* __restrict__ bias,
                                                float* __restrict__ C,
                                                int M, int N, int K) {
  __shared__ unsigned short sA[GBM * GBK];
  __shared__ unsigned short sB[GBN * GBK];
  int NX = N / GBN;
  int wgid = xcd_swz(blockIdx.x, gridDim.x);
  int y = wgid / NX, x = wgid - y * NX;
  int m0 = y * GBM, n0 = x * GBN;
  int tid = threadIdx.x;
  int wid = tid >> 6, lane = tid & 63;
  int wm = wid >> 1, wn = wid & 1;
  int lane31 = lane & 31, laneh = lane >> 5;
  f32x16 acc[2] = {};

  const unsigned short* aptr[4];
  const unsigned short* bptr[2];
#pragma unroll
  for (int r = 0; r < 4; ++r) {
    int c = (r * 4 + wid) * 64 + lane;
    int row = c >> 3, sl = c & 7;
    int sg = sl ^ (row & 7);
    aptr[r] = A + (size_t)(m0 + row) * K + sg * 8;
    if (r < 2) bptr[r] = Bt + (size_t)(n0 + row) * K + sg * 8;
  }

  for (int k0 = 0; k0 < K; k0 += GBK) {
#pragma unroll
    for (int r = 0; r < 4; ++r)
      __builtin_amdgcn_global_load_lds((const __attribute__((address_space(1))) unsigned int*)(aptr[r] + k0),
                                       (__attribute__((address_space(3))) unsigned int*)(sA + (r * 4 + wid) * 512),
                                       16, 0, 0);
#pragma unroll
    for (int r = 0; r < 2; ++r)
      __builtin_amdgcn_global_load_lds((const __attribute__((address_space(1))) unsigned int*)(bptr[r] + k0),
                                       (__attribute__((address_space(3))) unsigned int*)(sB + (r * 4 + wid) * 512),
                                       16, 0, 0);
    __syncthreads();
#pragma unroll
    for (int ks = 0; ks < 4; ++ks) {
      bf16x8 af[2], bfr;
#pragma unroll
      for (int i = 0; i < 2; ++i) {
        int row = wm * 64 + i * 32 + lane31;
        int slot = (ks * 2 + laneh) ^ (row & 7);
        af[i] = *reinterpret_cast<const bf16x8*>(sA + row * 64 + slot * 8);
      }
      {
        int rn = wn * 32 + lane31;
        int slot = (ks * 2 + laneh) ^ (rn & 7);
        bfr = *reinterpret_cast<const bf16x8*>(sB + rn * 64 + slot * 8);
      }
#pragma unroll
      for (int i = 0; i < 2; ++i)
        acc[i] = __builtin_amdgcn_mfma_f32_32x32x16_bf16(af[i], bfr, acc[i], 0, 0, 0);
    }
    __syncthreads();
  }

#pragma unroll
  for (int i = 0; i < 2; ++i) {
    int gcol = n0 + wn * 32 + lane31;
    float bv = bias[gcol];
#pragma unroll
    for (int r = 0; r < 16; ++r) {
      int gm = m0 + wm * 64 + i * 32 + (r & 3) + ((r >> 2) << 3) + (laneh << 2);
      if (gm >= M) continue;
      C[(size_t)gm * N + gcol] = acc[i][r] + bv;
    }
  }
}

// ---------------------------------------------------------------------------
// Kernel 5: criss-cross attention (round-12 lane-utilization version):
//  - staging over all 128 threads (640 coalesced 16B chunks)
//  - score phase over 120 threads (3 roles x ~14 keys; self-key = j==40)
//  - softmax: 2 passes; 1/sum folded into PV epilogue
//  - PV: 80 threads (2 d-halves), single inv multiply at store
// ---------------------------------------------------------------------------
__global__ __launch_bounds__(128) void attn3(const unsigned short* __restrict__ qb,
                                             const unsigned short* __restrict__ KVb,
                                             const float* __restrict__ mask,
                                             const int* __restrict__ pos2l,
                                             unsigned short* __restrict__ ctx,
                                             int n, int H) {
  __shared__ unsigned short Ks[40 * 72];
  __shared__ unsigned short Vs[40 * 72];
  __shared__ float S[40][44];
  __shared__ float Sinv[40];
  __shared__ float mrow[40];
  __shared__ int qlist[40];

  int bx = blockIdx.x;
  int r0 = bx % n;
  int h3 = (bx / n) % 3;
  int p = (bx / (3 * n)) % 4;
  int bi = bx / (12 * n);
  int h = p + 4 * h3;
  int nn = n * n;
  bool rowkeys = (p == 0 || p == 3);
  bool rowq = (p == 0 || p == 2);
  bool excl = (p < 2);
  int t = threadIdx.x;
  int H2 = 2 * H;

#pragma unroll
  for (int i = 0; i < 5; ++i) {
    int c2 = t + 128 * i;
    int jr = c2 >> 3, e8 = c2 & 7;
    int half = jr >= 40 ? 1 : 0;
    int j = jr - half * 40;
    int keypos = rowkeys ? (r0 * n + j) : (j * n + r0);
    int l2 = pos2l[bi * nn + keypos];
    bf16x8 v = {};
    if (l2 >= 0)
      v = *reinterpret_cast<const bf16x8*>(KVb + (size_t)l2 * H2 + half * H + h * 64 + e8 * 8);
    *reinterpret_cast<bf16x8*>((half ? Vs : Ks) + j * 72 + e8 * 8) = v;
  }
  if (t < 40) {
    mrow[t] = rowkeys ? mask[bi * nn + r0 * n + t] : mask[bi * nn + t * n + r0];
    int qpos = rowq ? (r0 * n + t) : (t * n + r0);
    qlist[t] = pos2l[bi * nn + qpos];
  }
  __syncthreads();

  int c = t % 40;
  int role = t / 40;
  int lq = (t < 120) ? qlist[c] : -1;

  if (lq >= 0) {
    float qf[64];
    const unsigned short* qp = qb + (size_t)lq * H + h * 64;
#pragma unroll
    for (int e8 = 0; e8 < 8; ++e8) {
      bf16x8 t8 = *reinterpret_cast<const bf16x8*>(qp + e8 * 8);
#pragma unroll
      for (int e = 0; e < 8; ++e) qf[e8 * 8 + e] = bf2f((unsigned short)t8[e]);
    }
    int j0 = role * 14;
    int j1 = j0 + 14; if (j1 > 40) j1 = 40;
    for (int j = j0; j < j1; ++j) {
      float acc = 0.f;
#pragma unroll
      for (int e8 = 0; e8 < 8; ++e8) {
        bf16x8 kv = *reinterpret_cast<const bf16x8*>(Ks + j * 72 + e8 * 8);
#pragma unroll
        for (int e = 0; e < 8; ++e) acc = fmaf(qf[e8 * 8 + e], bf2f((unsigned short)kv[e]), acc);
      }
      float mval = mrow[j] * ((excl && j == c) ? 0.f : 1.f);
      S[c][j] = acc * 0.125f + (1.f - mval) * -10000.f;
    }
    if (role == 2) {
      const unsigned short* kp = KVb + (size_t)lq * H2 + h * 64;
      float acc = 0.f;
#pragma unroll
      for (int e8 = 0; e8 < 8; ++e8) {
        bf16x8 kv = *reinterpret_cast<const bf16x8*>(kp + e8 * 8);
#pragma unroll
        for (int e = 0; e < 8; ++e) acc = fmaf(qf[e8 * 8 + e], bf2f((unsigned short)kv[e]), acc);
      }
      S[c][40] = acc * 0.125f + 1.0f;
    }
  }
  __syncthreads();

  if (t < 40 && qlist[t] >= 0) {
    float mx = S[t][0];
    for (int j = 1; j <= 40; ++j) mx = fmaxf(mx, S[t][j]);
    float sum = 0.f;
    for (int j = 0; j <= 40; ++j) { float e = __expf(S[t][j] - mx); S[t][j] = e; sum += e; }
    Sinv[t] = 1.f / sum;
  }
  __syncthreads();

  if (t < 80 && lq >= 0) {
    int d0 = role * 32;
    const unsigned short* vsp = KVb + (size_t)lq * H2 + H + h * 64 + d0;
    float pself = S[c][40];
    float inv = Sinv[c];
#pragma unroll
    for (int ch = 0; ch < 4; ++ch) {
      int dd = d0 + ch * 8;
      float facc[8];
      bf16x8 vself = *reinterpret_cast<const bf16x8*>(vsp + ch * 8);
#pragma unroll
      for (int e = 0; e < 8; ++e) facc[e] = pself * bf2f((unsigned short)vself[e]);
      for (int j = 0; j < 40; ++j) {
        float pj = S[c][j];
        bf16x8 vv = *reinterpret_cast<const bf16x8*>(Vs + j * 72 + dd);
#pragma unroll
        for (int e = 0; e < 8; ++e) facc[e] = fmaf(pj, bf2f((unsigned short)vv[e]), facc[e]);
      }
      bf16x8 st;
#pragma unroll
      for (int e = 0; e < 8; ++e) st[e] = f2bf(facc[e] * inv);
      *reinterpret_cast<bf16x8*>(ctx + (size_t)lq * H + h * 64 + dd) = st;
    }
  }
}

// ---------------------------------------------------------------------------
extern "C" void kernel_launch(void* const* d_in, const int* in_sizes, int n_in,
                              void* d_out, int out_size, void* d_ws, size_t ws_size,
                              hipStream_t stream) {
  const float* Input  = (const float*)d_in[0];
  const float* hidden = (const float*)d_in[1];
  const float* mask   = (const float*)d_in[2];
  const float* Wq = (const float*)d_in[3];
  const float* bq = (const float*)d_in[4];
  const float* Wk = (const float*)d_in[5];
  const float* bk = (const float*)d_in[6];
  const float* Wv = (const float*)d_in[7];
  const float* bv = (const float*)d_in[8];
  const float* Wo = (const float*)d_in[9];
  const float* bo = (const float*)d_in[10];

  int H = (int)llround(sqrt((double)in_sizes[3]));   // 768
  int total = in_sizes[2];                           // b*n*n = 3200
  int L = out_size / H;                              // 3120
  int bn = total - L;                                // b*n = 80
  int n = total / bn;                                // 40
  int b = bn / n;                                    // 2
  int mtiles = (L + QBM - 1) / QBM;                  // 25
  int Mpad = mtiles * QBM;                           // 3200
  size_t aElems = (size_t)Mpad * H;

  char* p = (char*)d_ws;
  auto take = [&](size_t bytes) { char* r = p; p += (bytes + 255) & ~(size_t)255; return r; };
  int* lidx  = (int*)take((size_t)L * 4);
  int* pos2l = (int*)take((size_t)total * 4);
  float* bkv = (float*)take((size_t)2 * H * 4);
  unsigned short* Wqt  = (unsigned short*)take((size_t)H * H * 2);
  unsigned short* Wot  = (unsigned short*)take((size_t)H * H * 2);
  unsigned short* Wkvt = (unsigned short*)take((size_t)2 * H * H * 2);
  unsigned short* qb2  = (unsigned short*)take(aElems * 2);
  unsigned short* KVb  = (unsigned short*)take(aElems * 2 * 2);
  unsigned short* ctxb = (unsigned short*)take(aElems * 2);

  int nt32 = H / 32;
  int nwconv = nt32 * nt32 * 4;                      // 2304
  prep<<<nwconv + 1, 256, 0, stream>>>(mask, total, pos2l, lidx, bk, bv, bkv,
                                       Wq, Wk, Wv, Wo,
                                       Wqt, Wkvt, Wkvt + (size_t)H * H, Wot, H);
  {
    int NX = 3 * H / QBN;                            // 18
    gemm_qkv<<<NX * mtiles, 256, 0, stream>>>(hidden, Input, Wqt, Wkvt, bq, bkv, lidx,
                                              qb2, KVb, L, H, H, NX);
  }
  attn3<<<b * 4 * 3 * n, 128, 0, stream>>>(qb2, KVb, mask, pos2l, ctxb, n, H);
  gemm_out<<<(H / GBN) * mtiles, 256, 0, stream>>>(ctxb, Wot, bo, (float*)d_out, L, H, H);
}